// Round 3
// baseline (773.415 us; speedup 1.0000x reference)
//
#include <hip/hip_runtime.h>
#include <math.h>

#define EMBED 384
#define HID 64
#define NE 4
#define TPB 256
#define TOK_PER_BLOCK (TPB / 2)   // 128: 2 threads per token (j-halves)

__global__ __launch_bounds__(TPB, 4) void router_main(
    const float* __restrict__ x, const float* __restrict__ lnw,
    const float* __restrict__ lnb, const float* __restrict__ w1,
    const float* __restrict__ w2, float* __restrict__ out,
    float* __restrict__ ws, int ntok)
{
  __shared__ float red[2 * NE];
  if (threadIdx.x < 2 * NE) red[threadIdx.x] = 0.f;
  __syncthreads();

  const int lane  = (int)(threadIdx.x & 63);
  const int gtid  = (int)(blockIdx.x * TPB + threadIdx.x);
  const int token = gtid >> 1;        // pair of lanes per token
  const int jhalf = gtid & 1;         // 0: j in [0,32), 1: j in [32,64)
  if (token >= ntok) return;

  const float* __restrict__ xrow = x + (size_t)token * EMBED;

  // ---- pass 1: LN stats (redundant across the lane pair; same cache lines) ----
  float s = 0.f, s2 = 0.f;
  for (int k = 0; k < EMBED / 4; ++k) {
    float4 v = reinterpret_cast<const float4*>(xrow)[k];
    s += (v.x + v.y) + (v.z + v.w);
    s2 = fmaf(v.x, v.x, s2); s2 = fmaf(v.y, v.y, s2);
    s2 = fmaf(v.z, v.z, s2); s2 = fmaf(v.w, v.w, s2);
  }
  const float mu   = s * (1.f / EMBED);
  const float var  = fmaf(-mu, mu, s2 * (1.f / EMBED));
  const float rstd = rsqrtf(var + 1e-5f);

  // ---- pass 2: GEMM1, this thread owns 32 hidden units ----
  float acc[HID / 2];
  #pragma unroll
  for (int j = 0; j < HID / 2; ++j) acc[j] = 0.f;

  const float* __restrict__ w1base = w1 + jhalf * (HID / 2);

  for (int dq = 0; dq < EMBED / 4; ++dq) {
    const int d = dq * 4;
    float4 v  = *reinterpret_cast<const float4*>(xrow + d);
    float4 lw = *reinterpret_cast<const float4*>(lnw + d);
    float4 lb = *reinterpret_cast<const float4*>(lnb + d);
    const float h0 = fmaf((v.x - mu) * rstd, lw.x, lb.x);
    const float h1 = fmaf((v.y - mu) * rstd, lw.y, lb.y);
    const float h2 = fmaf((v.z - mu) * rstd, lw.z, lb.z);
    const float h3 = fmaf((v.w - mu) * rstd, lw.w, lb.w);
    const float* __restrict__ w1r = w1base + (size_t)d * HID;
    #pragma unroll
    for (int jq = 0; jq < (HID / 2) / 4; ++jq) {
      float4 wa = *reinterpret_cast<const float4*>(w1r + jq * 4);
      float4 wb = *reinterpret_cast<const float4*>(w1r + HID + jq * 4);
      float4 wc = *reinterpret_cast<const float4*>(w1r + 2 * HID + jq * 4);
      float4 wd = *reinterpret_cast<const float4*>(w1r + 3 * HID + jq * 4);
      float a0 = acc[jq * 4 + 0], a1 = acc[jq * 4 + 1];
      float a2 = acc[jq * 4 + 2], a3 = acc[jq * 4 + 3];
      a0 = fmaf(h0, wa.x, a0); a1 = fmaf(h0, wa.y, a1);
      a2 = fmaf(h0, wa.z, a2); a3 = fmaf(h0, wa.w, a3);
      a0 = fmaf(h1, wb.x, a0); a1 = fmaf(h1, wb.y, a1);
      a2 = fmaf(h1, wb.z, a2); a3 = fmaf(h1, wb.w, a3);
      a0 = fmaf(h2, wc.x, a0); a1 = fmaf(h2, wc.y, a1);
      a2 = fmaf(h2, wc.z, a2); a3 = fmaf(h2, wc.w, a3);
      a0 = fmaf(h3, wd.x, a0); a1 = fmaf(h3, wd.y, a1);
      a2 = fmaf(h3, wd.z, a2); a3 = fmaf(h3, wd.w, a3);
      acc[jq * 4 + 0] = a0; acc[jq * 4 + 1] = a1;
      acc[jq * 4 + 2] = a2; acc[jq * 4 + 3] = a3;
    }
  }

  // ---- GELU(exact) + GEMM2 partial over this thread's 32 j's ----
  float logit[NE] = {0.f, 0.f, 0.f, 0.f};
  const float* __restrict__ w2base = w2 + jhalf * (HID / 2) * NE;
  #pragma unroll
  for (int jj = 0; jj < HID / 2; ++jj) {
    const float hv = acc[jj];
    const float g  = 0.5f * hv * (1.f + erff(hv * 0.7071067811865475f));
    float4 wv = *reinterpret_cast<const float4*>(w2base + jj * NE);
    logit[0] = fmaf(g, wv.x, logit[0]);
    logit[1] = fmaf(g, wv.y, logit[1]);
    logit[2] = fmaf(g, wv.z, logit[2]);
    logit[3] = fmaf(g, wv.w, logit[3]);
  }

  // ---- reduce across the lane pair ----
  #pragma unroll
  for (int e = 0; e < NE; ++e) logit[e] += __shfl_xor(logit[e], 1);

  // ---- temperature + softmax + argmax (both lanes compute; even lane stores) ----
  const float l0 = logit[0] * 0.5f, l1 = logit[1] * 0.5f,
              l2 = logit[2] * 0.5f, l3 = logit[3] * 0.5f;
  const float mx = fmaxf(fmaxf(l0, l1), fmaxf(l2, l3));
  const float e0 = expf(l0 - mx), e1 = expf(l1 - mx),
              e2 = expf(l2 - mx), e3 = expf(l3 - mx);
  const float inv = 1.f / (e0 + e1 + e2 + e3);
  const float p0 = e0 * inv, p1 = e1 * inv, p2 = e2 * inv, p3 = e3 * inv;

  int best = 0; float bp = p0;
  if (p1 > bp) { bp = p1; best = 1; }
  if (p2 > bp) { bp = p2; best = 2; }
  if (p3 > bp) { bp = p3; best = 3; }

  float psum[NE] = {0.f, 0.f, 0.f, 0.f};
  float pcnt[NE] = {0.f, 0.f, 0.f, 0.f};

  if (jhalf == 0) {
    *reinterpret_cast<float4*>(out + (size_t)token * 4) = make_float4(p0, p1, p2, p3);
    out[(size_t)ntok * 4 + token] = (float)best;
    float* o3 = out + (size_t)ntok * 5 + 1 + (size_t)token * 4;
    o3[0] = p0; o3[1] = p1; o3[2] = p2; o3[3] = p3;
    psum[0] = p0; psum[1] = p1; psum[2] = p2; psum[3] = p3;
    pcnt[best] = 1.f;
  }

  // ---- aux reduction: wave -> LDS -> global ----
  #pragma unroll
  for (int e = 0; e < NE; ++e) {
    float a = psum[e], c = pcnt[e];
    #pragma unroll
    for (int off = 32; off; off >>= 1) {
      a += __shfl_xor(a, off);
      c += __shfl_xor(c, off);
    }
    if (lane == 0) {
      atomicAdd(&red[e], a);
      atomicAdd(&red[NE + e], c);
    }
  }
  __syncthreads();
  if (threadIdx.x < 2 * NE) atomicAdd(&ws[threadIdx.x], red[threadIdx.x]);
}

__global__ void router_finalize(const float* __restrict__ ws,
                                float* __restrict__ out, int ntok)
{
  if (threadIdx.x == 0 && blockIdx.x == 0) {
    const float invN = 1.f / (float)ntok;
    float aux = 0.f;
    #pragma unroll
    for (int e = 0; e < NE; ++e)
      aux = fmaf(ws[NE + e] * invN, ws[e] * invN, aux);
    out[(size_t)ntok * 5] = (float)NE * aux;
  }
}

extern "C" void kernel_launch(void* const* d_in, const int* in_sizes, int n_in,
                              void* d_out, int out_size, void* d_ws, size_t ws_size,
                              hipStream_t stream) {
  const float* x   = (const float*)d_in[0];
  const float* lnw = (const float*)d_in[1];
  const float* lnb = (const float*)d_in[2];
  const float* w1  = (const float*)d_in[3];
  const float* w2  = (const float*)d_in[4];
  float* out = (float*)d_out;
  float* ws  = (float*)d_ws;

  const int ntok = in_sizes[0] / EMBED;   // 131072

  hipMemsetAsync(d_ws, 0, 2 * NE * sizeof(float), stream);

  const int blocks = (ntok + TOK_PER_BLOCK - 1) / TOK_PER_BLOCK;  // 1024
  router_main<<<blocks, TPB, 0, stream>>>(x, lnw, lnb, w1, w2, out, ws, ntok);
  router_finalize<<<1, 64, 0, stream>>>(ws, out, ntok);
}

// Round 4
// 182.279 us; speedup vs baseline: 4.2430x; 4.2430x over previous
//
#include <hip/hip_runtime.h>
#include <math.h>

#define EMBED 384
#define HID 64
#define NE 4
#define TPB 512
#define MT 4                   // tokens per thread
#define JS 4                   // j-split: threads per token group
#define JPT (HID / JS)         // 16 hidden units per thread
#define TOK_PER_BLOCK 512      // 512 threads / 4 jsplit * 4 tokens

// dynamic LDS: w1 (384*64 floats = 96 KB) + 8 floats aux reduction
#define SMEM_FLOATS (EMBED * HID + 2 * NE)

__global__ __launch_bounds__(TPB, 1) void router_main(
    const float* __restrict__ x, const float* __restrict__ lnw,
    const float* __restrict__ lnb, const float* __restrict__ w1,
    const float* __restrict__ w2, float* __restrict__ out,
    float* __restrict__ ws, int ntok)
{
  extern __shared__ float smem[];
  float* w1s = smem;                    // [EMBED][HID]
  float* red = smem + EMBED * HID;      // [8]

  const int tid = (int)threadIdx.x;

  // ---- stage w1 into LDS, fully coalesced (12 float4 per thread) ----
  {
    const float4* src = reinterpret_cast<const float4*>(w1);
    float4* dst = reinterpret_cast<float4*>(w1s);
    #pragma unroll
    for (int k = 0; k < (EMBED * HID / 4) / TPB; ++k) {
      const int f4 = tid + k * TPB;
      dst[f4] = src[f4];
    }
  }
  if (tid < 2 * NE) red[tid] = 0.f;
  __syncthreads();

  const int lane = tid & 63;
  const int wv   = tid >> 6;
  const int tg   = lane >> 2;       // 16 token groups per wave
  const int jg   = lane & 3;        // j-quarter
  const int wbase = (int)blockIdx.x * TOK_PER_BLOCK + wv * 64;
  const int t0    = wbase + tg * MT;           // this thread's 4 tokens: t0..t0+3

  const float* __restrict__ xrow = x + (size_t)t0 * EMBED;

  // ---- LN stats: d-sliced across the 4-lane group, shfl-combined ----
  float s[MT]  = {0.f, 0.f, 0.f, 0.f};
  float s2[MT] = {0.f, 0.f, 0.f, 0.f};
  {
    const float* xs = xrow + jg * (EMBED / JS);   // 96-float slice
    for (int k = 0; k < (EMBED / JS) / 4; ++k) {
      #pragma unroll
      for (int m = 0; m < MT; ++m) {
        float4 v = reinterpret_cast<const float4*>(xs + (size_t)m * EMBED)[k];
        s[m] += (v.x + v.y) + (v.z + v.w);
        s2[m] = fmaf(v.x, v.x, s2[m]); s2[m] = fmaf(v.y, v.y, s2[m]);
        s2[m] = fmaf(v.z, v.z, s2[m]); s2[m] = fmaf(v.w, v.w, s2[m]);
      }
    }
  }
  float mu[MT], rstd[MT];
  #pragma unroll
  for (int m = 0; m < MT; ++m) {
    s[m]  += __shfl_xor(s[m], 1);  s[m]  += __shfl_xor(s[m], 2);
    s2[m] += __shfl_xor(s2[m], 1); s2[m] += __shfl_xor(s2[m], 2);
    mu[m] = s[m] * (1.f / EMBED);
    const float var = fmaf(-mu[m], mu[m], s2[m] * (1.f / EMBED));
    rstd[m] = rsqrtf(var + 1e-5f);
  }

  // ---- GEMM1: acc[m][jj], jj over this lane's 16 hidden units ----
  float acc[MT][JPT];
  #pragma unroll
  for (int m = 0; m < MT; ++m)
    #pragma unroll
    for (int j = 0; j < JPT; ++j) acc[m][j] = 0.f;

  const int joff = jg * JPT;

  for (int d = 0; d < EMBED; d += 4) {
    float4 lw = *reinterpret_cast<const float4*>(lnw + d);   // uniform
    float4 lb = *reinterpret_cast<const float4*>(lnb + d);   // uniform
    float4 xv[MT];
    #pragma unroll
    for (int m = 0; m < MT; ++m)
      xv[m] = *reinterpret_cast<const float4*>(xrow + (size_t)m * EMBED + d);
    float h[MT][4];
    #pragma unroll
    for (int m = 0; m < MT; ++m) {
      h[m][0] = fmaf((xv[m].x - mu[m]) * rstd[m], lw.x, lb.x);
      h[m][1] = fmaf((xv[m].y - mu[m]) * rstd[m], lw.y, lb.y);
      h[m][2] = fmaf((xv[m].z - mu[m]) * rstd[m], lw.z, lb.z);
      h[m][3] = fmaf((xv[m].w - mu[m]) * rstd[m], lw.w, lb.w);
    }
    #pragma unroll
    for (int dd = 0; dd < 4; ++dd) {
      const float* wr = w1s + (d + dd) * HID + joff;
      float4 w0 = *reinterpret_cast<const float4*>(wr);
      float4 w4 = *reinterpret_cast<const float4*>(wr + 4);
      float4 w8 = *reinterpret_cast<const float4*>(wr + 8);
      float4 wc = *reinterpret_cast<const float4*>(wr + 12);
      #pragma unroll
      for (int m = 0; m < MT; ++m) {
        const float hh = h[m][dd];
        acc[m][0]  = fmaf(hh, w0.x, acc[m][0]);
        acc[m][1]  = fmaf(hh, w0.y, acc[m][1]);
        acc[m][2]  = fmaf(hh, w0.z, acc[m][2]);
        acc[m][3]  = fmaf(hh, w0.w, acc[m][3]);
        acc[m][4]  = fmaf(hh, w4.x, acc[m][4]);
        acc[m][5]  = fmaf(hh, w4.y, acc[m][5]);
        acc[m][6]  = fmaf(hh, w4.z, acc[m][6]);
        acc[m][7]  = fmaf(hh, w4.w, acc[m][7]);
        acc[m][8]  = fmaf(hh, w8.x, acc[m][8]);
        acc[m][9]  = fmaf(hh, w8.y, acc[m][9]);
        acc[m][10] = fmaf(hh, w8.z, acc[m][10]);
        acc[m][11] = fmaf(hh, w8.w, acc[m][11]);
        acc[m][12] = fmaf(hh, wc.x, acc[m][12]);
        acc[m][13] = fmaf(hh, wc.y, acc[m][13]);
        acc[m][14] = fmaf(hh, wc.z, acc[m][14]);
        acc[m][15] = fmaf(hh, wc.w, acc[m][15]);
      }
    }
  }

  // ---- GELU(exact) + GEMM2 partials over this lane's 16 j's ----
  float logit[MT][NE];
  #pragma unroll
  for (int m = 0; m < MT; ++m)
    #pragma unroll
    for (int e = 0; e < NE; ++e) logit[m][e] = 0.f;

  #pragma unroll
  for (int jj = 0; jj < JPT; ++jj) {
    float4 wv = *reinterpret_cast<const float4*>(w2 + (size_t)(joff + jj) * NE);
    #pragma unroll
    for (int m = 0; m < MT; ++m) {
      const float hv = acc[m][jj];
      const float g  = 0.5f * hv * (1.f + erff(hv * 0.7071067811865475f));
      logit[m][0] = fmaf(g, wv.x, logit[m][0]);
      logit[m][1] = fmaf(g, wv.y, logit[m][1]);
      logit[m][2] = fmaf(g, wv.z, logit[m][2]);
      logit[m][3] = fmaf(g, wv.w, logit[m][3]);
    }
  }

  // ---- reduce logits across the 4-lane group ----
  #pragma unroll
  for (int m = 0; m < MT; ++m)
    #pragma unroll
    for (int e = 0; e < NE; ++e) {
      logit[m][e] += __shfl_xor(logit[m][e], 1);
      logit[m][e] += __shfl_xor(logit[m][e], 2);
    }

  // lane handles token t0 + jg: static select of m == jg (no runtime reg index)
  float l[NE];
  #pragma unroll
  for (int e = 0; e < NE; ++e) {
    float v = logit[0][e];
    v = (jg == 1) ? logit[1][e] : v;
    v = (jg == 2) ? logit[2][e] : v;
    v = (jg == 3) ? logit[3][e] : v;
    l[e] = v * 0.5f;   // /T, T=2
  }
  const int mytok = t0 + jg;   // == wbase + lane -> coalesced stores

  const float mx = fmaxf(fmaxf(l[0], l[1]), fmaxf(l[2], l[3]));
  const float e0 = expf(l[0] - mx), e1 = expf(l[1] - mx),
              e2 = expf(l[2] - mx), e3 = expf(l[3] - mx);
  const float inv = 1.f / (e0 + e1 + e2 + e3);
  const float p0 = e0 * inv, p1 = e1 * inv, p2 = e2 * inv, p3 = e3 * inv;

  int best = 0; float bp = p0;
  if (p1 > bp) { bp = p1; best = 1; }
  if (p2 > bp) { bp = p2; best = 2; }
  if (p3 > bp) { bp = p3; best = 3; }

  if (mytok < ntok) {
    *reinterpret_cast<float4*>(out + (size_t)mytok * 4) = make_float4(p0, p1, p2, p3);
    out[(size_t)ntok * 4 + mytok] = (float)best;
    float* o3 = out + (size_t)ntok * 5 + 1 + (size_t)mytok * 4;
    o3[0] = p0; o3[1] = p1; o3[2] = p2; o3[3] = p3;
  }

  // ---- aux reduction: wave (64 tokens) -> LDS -> global ----
  float psum[NE] = {p0, p1, p2, p3};
  float pcnt[NE] = {0.f, 0.f, 0.f, 0.f};
  pcnt[0] = (best == 0) ? 1.f : 0.f;
  pcnt[1] = (best == 1) ? 1.f : 0.f;
  pcnt[2] = (best == 2) ? 1.f : 0.f;
  pcnt[3] = (best == 3) ? 1.f : 0.f;

  #pragma unroll
  for (int e = 0; e < NE; ++e) {
    float a = psum[e], c = pcnt[e];
    #pragma unroll
    for (int off = 32; off; off >>= 1) {
      a += __shfl_xor(a, off);
      c += __shfl_xor(c, off);
    }
    if (lane == 0) {
      atomicAdd(&red[e], a);
      atomicAdd(&red[NE + e], c);
    }
  }
  __syncthreads();
  if (tid < 2 * NE) atomicAdd(&ws[tid], red[tid]);
}

__global__ void router_finalize(const float* __restrict__ ws,
                                float* __restrict__ out, int ntok)
{
  if (threadIdx.x == 0 && blockIdx.x == 0) {
    const float invN = 1.f / (float)ntok;
    float aux = 0.f;
    #pragma unroll
    for (int e = 0; e < NE; ++e)
      aux = fmaf(ws[NE + e] * invN, ws[e] * invN, aux);
    out[(size_t)ntok * 5] = (float)NE * aux;
  }
}

extern "C" void kernel_launch(void* const* d_in, const int* in_sizes, int n_in,
                              void* d_out, int out_size, void* d_ws, size_t ws_size,
                              hipStream_t stream) {
  const float* x   = (const float*)d_in[0];
  const float* lnw = (const float*)d_in[1];
  const float* lnb = (const float*)d_in[2];
  const float* w1  = (const float*)d_in[3];
  const float* w2  = (const float*)d_in[4];
  float* out = (float*)d_out;
  float* ws  = (float*)d_ws;

  const int ntok = in_sizes[0] / EMBED;   // 131072

  hipMemsetAsync(d_ws, 0, 2 * NE * sizeof(float), stream);

  const int blocks = (ntok + TOK_PER_BLOCK - 1) / TOK_PER_BLOCK;  // 256
  const size_t smem_bytes = SMEM_FLOATS * sizeof(float);          // ~96 KB
  router_main<<<blocks, TPB, smem_bytes, stream>>>(x, lnw, lnb, w1, w2, out, ws, ntok);
  router_finalize<<<1, 64, 0, stream>>>(ws, out, ntok);
}

// Round 5
// 114.544 us; speedup vs baseline: 6.7521x; 1.5913x over previous
//
#include <hip/hip_runtime.h>
#include <math.h>

#define EMBED 384
#define HID 64
#define NE 4
#define TPB 512
#define MT 4                  // tokens per thread
#define JS 4                  // lanes (j-slices) per token group
#define JPT 16                // hidden units per thread
#define TOKB 512              // tokens per block

// LDS floats: wln[384*64] + w2s[256] + c1s[64] + c2s[64] + part[2*512] + red[8]
#define WLN_F   (EMBED * HID)          // 24576
#define W2_OFF  (WLN_F)                // 256
#define C1_OFF  (W2_OFF + HID * NE)    // 64
#define C2_OFF  (C1_OFF + HID)         // 64
#define PART_OFF (C2_OFF + HID)        // 1024
#define RED_OFF (PART_OFF + 2 * TPB)   // 8
#define SMEM_FLOATS (RED_OFF + 2 * NE)

__global__ void
__attribute__((amdgpu_flat_work_group_size(TPB, TPB), amdgpu_waves_per_eu(2, 2)))
router_main(
    const float* __restrict__ x, const float* __restrict__ lnw,
    const float* __restrict__ lnb, const float* __restrict__ w1,
    const float* __restrict__ w2, float* __restrict__ out,
    float* __restrict__ ws, int ntok)
{
  extern __shared__ float smem[];
  float* wln = smem;
  float* w2s = smem + W2_OFF;
  float* c1s = smem + C1_OFF;
  float* c2s = smem + C2_OFF;
  float* part = smem + PART_OFF;
  float* red = smem + RED_OFF;

  const int tid = (int)threadIdx.x;

  // ---- stage wln = lnw[d] * w1[d][j] into LDS (12 float4 / thread) ----
  {
    const float4* src = reinterpret_cast<const float4*>(w1);
    float4* dst = reinterpret_cast<float4*>(wln);
    #pragma unroll
    for (int k = 0; k < (WLN_F / 4) / TPB; ++k) {
      const int f4 = tid + k * TPB;
      const float sc = lnw[f4 >> 4];          // d = f4/16 (16 float4 per row)
      float4 v = src[f4];
      v.x *= sc; v.y *= sc; v.z *= sc; v.w *= sc;
      dst[f4] = v;
    }
  }
  if (tid < HID * NE / 4) {                   // stage w2 (64 float4)
    reinterpret_cast<float4*>(w2s)[tid] = reinterpret_cast<const float4*>(w2)[tid];
  }
  if (tid < 2 * NE) red[tid] = 0.f;
  __syncthreads();

  // ---- cooperative c1[j] = sum_d wln[d][j]; c2[j] = sum_d lnb[d]*w1[d][j] ----
  {
    const int j = tid & 63;
    const int dpart = tid >> 6;               // 8 parts x 48 d's
    float c1p = 0.f, c2p = 0.f;
    #pragma unroll 8
    for (int k = 0; k < EMBED / 8; ++k) {
      const int d = dpart * (EMBED / 8) + k;
      c1p += wln[d * HID + j];
      c2p = fmaf(lnb[d], w1[d * HID + j], c2p);
    }
    part[dpart * 64 + j] = c1p;
    part[TPB + dpart * 64 + j] = c2p;
  }
  __syncthreads();
  if (tid < HID) {
    float a = 0.f, b = 0.f;
    #pragma unroll
    for (int p = 0; p < 8; ++p) {
      a += part[p * 64 + tid];
      b += part[TPB + p * 64 + tid];
    }
    c1s[tid] = a;
    c2s[tid] = b;
  }
  __syncthreads();

  // ---- token/lane mapping ----
  const int lane = tid & 63;
  const int wv = tid >> 6;                    // 8 waves
  const int tg = lane >> 2;                   // 16 groups/wave
  const int jg = lane & 3;
  const int wbase = (int)blockIdx.x * TOKB + wv * 64;
  const int t0 = wbase + tg * MT;             // this thread's 4 tokens
  const int joff = jg * JPT;

  const float* __restrict__ xrow = x + (size_t)t0 * EMBED;

  // ---- fused single pass: s, s2, and GEMM1 accumulators ----
  float acc[MT][JPT];
  #pragma unroll
  for (int m = 0; m < MT; ++m)
    #pragma unroll
    for (int j = 0; j < JPT; ++j) acc[m][j] = 0.f;
  float s[MT] = {0.f, 0.f, 0.f, 0.f};
  float s2[MT] = {0.f, 0.f, 0.f, 0.f};

  #pragma unroll 2
  for (int dq = 0; dq < EMBED / 4; ++dq) {
    const int d = dq * 4;
    float4 xv[MT];
    #pragma unroll
    for (int m = 0; m < MT; ++m)
      xv[m] = *reinterpret_cast<const float4*>(xrow + (size_t)m * EMBED + d);
    #pragma unroll
    for (int m = 0; m < MT; ++m) {
      s[m] += (xv[m].x + xv[m].y) + (xv[m].z + xv[m].w);
      s2[m] = fmaf(xv[m].x, xv[m].x, s2[m]);
      s2[m] = fmaf(xv[m].y, xv[m].y, s2[m]);
      s2[m] = fmaf(xv[m].z, xv[m].z, s2[m]);
      s2[m] = fmaf(xv[m].w, xv[m].w, s2[m]);
    }
    #pragma unroll
    for (int dd = 0; dd < 4; ++dd) {
      const float* wr = wln + (d + dd) * HID + joff;
      float4 w0 = *reinterpret_cast<const float4*>(wr);
      float4 w4 = *reinterpret_cast<const float4*>(wr + 4);
      float4 w8 = *reinterpret_cast<const float4*>(wr + 8);
      float4 wc = *reinterpret_cast<const float4*>(wr + 12);
      #pragma unroll
      for (int m = 0; m < MT; ++m) {
        const float xx = (dd == 0) ? xv[m].x : (dd == 1) ? xv[m].y
                       : (dd == 2) ? xv[m].z : xv[m].w;
        acc[m][0]  = fmaf(xx, w0.x, acc[m][0]);
        acc[m][1]  = fmaf(xx, w0.y, acc[m][1]);
        acc[m][2]  = fmaf(xx, w0.z, acc[m][2]);
        acc[m][3]  = fmaf(xx, w0.w, acc[m][3]);
        acc[m][4]  = fmaf(xx, w4.x, acc[m][4]);
        acc[m][5]  = fmaf(xx, w4.y, acc[m][5]);
        acc[m][6]  = fmaf(xx, w4.z, acc[m][6]);
        acc[m][7]  = fmaf(xx, w4.w, acc[m][7]);
        acc[m][8]  = fmaf(xx, w8.x, acc[m][8]);
        acc[m][9]  = fmaf(xx, w8.y, acc[m][9]);
        acc[m][10] = fmaf(xx, w8.z, acc[m][10]);
        acc[m][11] = fmaf(xx, w8.w, acc[m][11]);
        acc[m][12] = fmaf(xx, wc.x, acc[m][12]);
        acc[m][13] = fmaf(xx, wc.y, acc[m][13]);
        acc[m][14] = fmaf(xx, wc.z, acc[m][14]);
        acc[m][15] = fmaf(xx, wc.w, acc[m][15]);
      }
    }
  }

  // ---- epilogue: LN-correct, GELU, GEMM2 partials ----
  float logit[MT][NE];
  #pragma unroll
  for (int m = 0; m < MT; ++m) {
    const float mu = s[m] * (1.f / EMBED);
    const float var = fmaf(-mu, mu, s2[m] * (1.f / EMBED));
    const float rstd = rsqrtf(var + 1e-5f);
    #pragma unroll
    for (int e = 0; e < NE; ++e) logit[m][e] = 0.f;
    #pragma unroll
    for (int jj = 0; jj < JPT; ++jj) {
      const int j = joff + jj;
      const float hid = fmaf(rstd, fmaf(-mu, c1s[j], acc[m][jj]), 0.f) + c2s[j];
      const float g = 0.5f * hid * (1.f + erff(hid * 0.7071067811865475f));
      float4 wv = *reinterpret_cast<const float4*>(w2s + j * NE);
      logit[m][0] = fmaf(g, wv.x, logit[m][0]);
      logit[m][1] = fmaf(g, wv.y, logit[m][1]);
      logit[m][2] = fmaf(g, wv.z, logit[m][2]);
      logit[m][3] = fmaf(g, wv.w, logit[m][3]);
    }
  }

  // ---- reduce logits across the 4-lane group ----
  #pragma unroll
  for (int m = 0; m < MT; ++m)
    #pragma unroll
    for (int e = 0; e < NE; ++e) {
      logit[m][e] += __shfl_xor(logit[m][e], 1);
      logit[m][e] += __shfl_xor(logit[m][e], 2);
    }

  // lane jg takes token t0+jg -> mytok == wbase + lane (coalesced)
  float l[NE];
  #pragma unroll
  for (int e = 0; e < NE; ++e) {
    float v = logit[0][e];
    v = (jg == 1) ? logit[1][e] : v;
    v = (jg == 2) ? logit[2][e] : v;
    v = (jg == 3) ? logit[3][e] : v;
    l[e] = v * 0.5f;                          // /T, T=2
  }
  const int mytok = wbase + lane;

  const float mx = fmaxf(fmaxf(l[0], l[1]), fmaxf(l[2], l[3]));
  const float e0 = expf(l[0] - mx), e1 = expf(l[1] - mx),
              e2 = expf(l[2] - mx), e3 = expf(l[3] - mx);
  const float inv = 1.f / (e0 + e1 + e2 + e3);
  const float p0 = e0 * inv, p1 = e1 * inv, p2 = e2 * inv, p3 = e3 * inv;

  int best = 0; float bp = p0;
  if (p1 > bp) { bp = p1; best = 1; }
  if (p2 > bp) { bp = p2; best = 2; }
  if (p3 > bp) { bp = p3; best = 3; }

  if (mytok < ntok) {
    *reinterpret_cast<float4*>(out + (size_t)mytok * 4) = make_float4(p0, p1, p2, p3);
    out[(size_t)ntok * 4 + mytok] = (float)best;
    float* o3 = out + (size_t)ntok * 5 + 1 + (size_t)mytok * 4;
    o3[0] = p0; o3[1] = p1; o3[2] = p2; o3[3] = p3;
  }

  // ---- aux reduction: wave -> LDS -> global ----
  float psum[NE] = {p0, p1, p2, p3};
  float pcnt[NE];
  pcnt[0] = (best == 0) ? 1.f : 0.f;
  pcnt[1] = (best == 1) ? 1.f : 0.f;
  pcnt[2] = (best == 2) ? 1.f : 0.f;
  pcnt[3] = (best == 3) ? 1.f : 0.f;

  #pragma unroll
  for (int e = 0; e < NE; ++e) {
    float a = psum[e], c = pcnt[e];
    #pragma unroll
    for (int off = 32; off; off >>= 1) {
      a += __shfl_xor(a, off);
      c += __shfl_xor(c, off);
    }
    if (lane == 0) {
      atomicAdd(&red[e], a);
      atomicAdd(&red[NE + e], c);
    }
  }
  __syncthreads();
  if (tid < 2 * NE) atomicAdd(&ws[tid], red[tid]);
}

__global__ void router_finalize(const float* __restrict__ ws,
                                float* __restrict__ out, int ntok)
{
  if (threadIdx.x == 0 && blockIdx.x == 0) {
    const float invN = 1.f / (float)ntok;
    float aux = 0.f;
    #pragma unroll
    for (int e = 0; e < NE; ++e)
      aux = fmaf(ws[NE + e] * invN, ws[e] * invN, aux);
    out[(size_t)ntok * 5] = (float)NE * aux;
  }
}

extern "C" void kernel_launch(void* const* d_in, const int* in_sizes, int n_in,
                              void* d_out, int out_size, void* d_ws, size_t ws_size,
                              hipStream_t stream) {
  const float* x   = (const float*)d_in[0];
  const float* lnw = (const float*)d_in[1];
  const float* lnb = (const float*)d_in[2];
  const float* w1  = (const float*)d_in[3];
  const float* w2  = (const float*)d_in[4];
  float* out = (float*)d_out;
  float* ws  = (float*)d_ws;

  const int ntok = in_sizes[0] / EMBED;   // 131072

  hipMemsetAsync(d_ws, 0, 2 * NE * sizeof(float), stream);

  const int blocks = (ntok + TOKB - 1) / TOKB;             // 256
  const size_t smem_bytes = SMEM_FLOATS * sizeof(float);   // ~102 KB
  router_main<<<blocks, TPB, smem_bytes, stream>>>(x, lnw, lnb, w1, w2, out, ws, ntok);
  router_finalize<<<1, 64, 0, stream>>>(ws, out, ntok);
}